// Round 4
// baseline (199.628 us; speedup 1.0000x reference)
//
#include <hip/hip_runtime.h>
#include <math.h>

#define B_CONST 256
#define V_CONST 128000
#define L_CONST 200
#define F4_PER_ROW 32000
#define F4_PER_WAVE 4000         // 8 waves per row, 62.5 KB each
#define WPR 8                    // waves per row

typedef float f32x4 __attribute__((ext_vector_type(4)));

// ws layout: int partial[B*WPR], int sub[B], int dist[B]

__device__ __forceinline__ int cnt4(const f32x4 v, const float p) {
    int c = 0;
    c += __popcll(__ballot(v[0] > p));
    c += __popcll(__ballot(v[1] > p));
    c += __popcll(__ballot(v[2] > p));
    c += __popcll(__ballot(v[3] > p));
    return c;
}

// grid 512 x block 256 (4 waves): 2048 waves = one residency round on 256 CUs.
// Row b is handled by blocks 2b, 2b+1; wave slot t = (blockIdx.x&1)*4 + wave
// streams f4 range [t*4000, (t+1)*4000) of row b via an 8-deep double-buffered
// non-temporal load pipeline. Slot 0 additionally does the history dedup.
// Zero barriers, zero LDS; counts accumulate on the scalar pipe (ballot+popc).
__global__ __launch_bounds__(256) void rank_count_kernel(
    const float* __restrict__ scores,
    const int* __restrict__ labels,
    const int* __restrict__ seqs,
    int* __restrict__ partial,
    int* __restrict__ subv,
    int* __restrict__ distv)
{
    const int tid  = threadIdx.x;
    const int lane = tid & 63;
    const int w    = tid >> 6;
    const int b    = blockIdx.x >> 1;
    const int t    = ((blockIdx.x & 1) << 2) + w;   // wave slot in row, 0..7

    const float* row = scores + (size_t)b * V_CONST;

    // ---- history loads first (slot 0 only) so gathers overlap streaming
    int   hval[4];
    float hsv[4];
    const bool histw = (t == 0);
    if (histw) {
        const int* sq = seqs + b * L_CONST;
        #pragma unroll
        for (int k = 0; k < 4; ++k) {
            const int e = lane + 64 * k;
            hval[k] = (e < L_CONST) ? sq[e] : -1;
            hsv[k]  = (e < L_CONST) ? row[hval[k]] : 0.0f;
        }
    }

    const float predict = row[labels[b]];

    // ---- streaming count: 4000 f4 per wave = 62 full 64-f4 rounds + 32 tail
    const f32x4* row4 = (const f32x4*)row;     // already offset to row b
    const int base = t * F4_PER_WAVE + lane;   // f4 units within the row

    f32x4 A[8], Bv[8];
    #pragma unroll
    for (int j = 0; j < 8; ++j)
        A[j] = __builtin_nontemporal_load(row4 + base + j * 64);

    int cnt = 0;
    #pragma unroll
    for (int kb = 8; kb <= 40; kb += 16) {        // kb = 8, 24, 40
        #pragma unroll
        for (int j = 0; j < 8; ++j)
            Bv[j] = __builtin_nontemporal_load(row4 + base + (kb + j) * 64);
        #pragma unroll
        for (int j = 0; j < 8; ++j) cnt += cnt4(A[j], predict);
        #pragma unroll
        for (int j = 0; j < 8; ++j)
            A[j] = __builtin_nontemporal_load(row4 + base + (kb + 8 + j) * 64);
        #pragma unroll
        for (int j = 0; j < 8; ++j) cnt += cnt4(Bv[j], predict);
    }
    // A holds k=48..55. Remaining: k=56..61 plus the 32-f4 tail (lanes<32).
    #pragma unroll
    for (int j = 0; j < 6; ++j)
        Bv[j] = __builtin_nontemporal_load(row4 + base + (56 + j) * 64);
    f32x4 tl = {0.0f, 0.0f, 0.0f, 0.0f};
    if (lane < 32)
        tl = __builtin_nontemporal_load(row4 + base + 62 * 64);
    #pragma unroll
    for (int j = 0; j < 8; ++j) cnt += cnt4(A[j], predict);
    #pragma unroll
    for (int j = 0; j < 6; ++j) cnt += cnt4(Bv[j], predict);
    {
        const bool m = lane < 32;
        cnt += __popcll(__ballot(m && (tl[0] > predict)));
        cnt += __popcll(__ballot(m && (tl[1] > predict)));
        cnt += __popcll(__ballot(m && (tl[2] > predict)));
        cnt += __popcll(__ballot(m && (tl[3] > predict)));
    }
    if (lane == 0) partial[b * WPR + t] = cnt;

    // ---- history dedup (slot 0): in-register via shfl broadcast
    if (histw) {
        bool first[4] = {true, true, true, true};
        #pragma unroll
        for (int jb = 0; jb < 4; ++jb) {
            for (int l = 0; l < 64; ++l) {
                const int j  = jb * 64 + l;
                const int sj = __shfl(hval[jb], l);
                #pragma unroll
                for (int k = jb; k < 4; ++k) {
                    const int e = lane + 64 * k;
                    if (j < e && sj == hval[k]) first[k] = false;
                }
            }
        }
        int d = 0, s = 0;
        #pragma unroll
        for (int k = 0; k < 4; ++k) {
            const int  e   = lane + 64 * k;
            const bool isd = first[k] && (e < L_CONST);
            d += __popcll(__ballot(isd));
            s += __popcll(__ballot(isd && (hsv[k] > predict)));
        }
        if (lane == 0) { distv[b] = d; subv[b] = s; }
    }
}

// single wave, 64 threads, 4 rows per lane, zero barriers
__global__ __launch_bounds__(64) void finalize_kernel(
    const int* __restrict__ partial,
    const int* __restrict__ subv,
    const int* __restrict__ distv,
    float* __restrict__ out)
{
    const int l = threadIdx.x;               // 0..63

    float acc[12];
    #pragma unroll
    for (int q = 0; q < 12; ++q) acc[q] = 0.0f;

    const float ks[5] = {1.0f, 5.0f, 10.0f, 20.0f, 50.0f};

    #pragma unroll
    for (int r = 0; r < 4; ++r) {
        const int b = l + 64 * r;            // coalesced within the wave
        int gt = 0;
        #pragma unroll
        for (int s = 0; s < WPR; ++s) gt += partial[b * WPR + s];
        const float rank  = (float)(gt - subv[b]);
        const float valid = (float)(V_CONST - distv[b]);

        const float invlog = 1.0f / log2f(rank + 2.0f);
        #pragma unroll
        for (int i = 0; i < 5; ++i) {
            const float ind = (rank < ks[i]) ? 1.0f : 0.0f;
            acc[2 * i]     += ind * invlog;  // NDCG@k
            acc[2 * i + 1] += ind;           // Recall@k
        }
        acc[10] += 1.0f / (rank + 1.0f);     // MRR
        acc[11] += 1.0f - rank / valid;      // AUC-like
    }

    #pragma unroll
    for (int q = 0; q < 12; ++q) {
        float v = acc[q];
        #pragma unroll
        for (int off = 32; off > 0; off >>= 1)
            v += __shfl_down(v, off, 64);
        if (l == 0) out[q] = v * (1.0f / B_CONST);
    }
    if (l == 0) out[12] = 0.0f;
}

extern "C" void kernel_launch(void* const* d_in, const int* in_sizes, int n_in,
                              void* d_out, int out_size, void* d_ws, size_t ws_size,
                              hipStream_t stream) {
    const float* scores = (const float*)d_in[0];
    const int*   labels = (const int*)d_in[1];
    const int*   seqs   = (const int*)d_in[2];
    float* out = (float*)d_out;
    int*   ws  = (int*)d_ws;

    int* partial = ws;                               // B*WPR
    int* subv    = ws + B_CONST * WPR;               // B
    int* distv   = ws + B_CONST * WPR + B_CONST;     // B

    rank_count_kernel<<<dim3(2 * B_CONST), 256, 0, stream>>>(
        scores, labels, seqs, partial, subv, distv);
    finalize_kernel<<<1, 64, 0, stream>>>(partial, subv, distv, out);
}